// Round 4
// baseline (198.184 us; speedup 1.0000x reference)
//
#include <hip/hip_runtime.h>
#include <hip/hip_bf16.h>
#include <cstddef>
#include <cstdint>

typedef float v4f __attribute__((ext_vector_type(4)));
typedef short v8s __attribute__((ext_vector_type(8)));

__device__ __forceinline__ short f2bf(float x) {
    __hip_bfloat16 h = __float2bfloat16(x);
    short s; __builtin_memcpy(&s, &h, 2); return s;
}
__device__ __forceinline__ float bf2f(short s) {
    __hip_bfloat16 h; __builtin_memcpy(&h, &s, 2);
    return __bfloat162float(h);
}
__device__ __forceinline__ void gld16(const void* g, void* l) {
    __builtin_amdgcn_global_load_lds(
        (const __attribute__((address_space(1))) unsigned int*)g,
        (__attribute__((address_space(3))) unsigned int*)l, 16, 0, 0);
}
#define MFMA(a,b,c) __builtin_amdgcn_mfma_f32_16x16x32_bf16((a),(b),(c),0,0,0)

// ---------------------------------------------------------------------------
// CPB MLP with LDS-staged weights: table[h][r] = fc2(relu(fc1(rct[r])))
// ---------------------------------------------------------------------------
__global__ __launch_bounds__(256)
void cpb_kernel(const float* __restrict__ rct,
                const float* __restrict__ fc1w, const float* __restrict__ fc1b,
                const float* __restrict__ fc2w, const float* __restrict__ fc2b,
                float* __restrict__ table)
{
    __shared__ float s1[1024];
    __shared__ float sb[512];
    __shared__ float s2[4096];
    int tid = threadIdx.x;
    for (int i = tid; i < 1024; i += 256) s1[i] = fc1w[i];
    for (int i = tid; i < 512;  i += 256) sb[i] = fc1b[i];
    for (int i = tid; i < 4096; i += 256) s2[i] = fc2w[i];
    __syncthreads();
    int r = blockIdx.x * 256 + tid;
    bool ok = r < 3969;
    float c0 = ok ? rct[2*r]   : 0.f;
    float c1 = ok ? rct[2*r+1] : 0.f;
    float a[8] = {0,0,0,0,0,0,0,0};
    for (int j = 0; j < 512; ++j) {
        float hv = fmaxf(c0*s1[2*j] + c1*s1[2*j+1] + sb[j], 0.0f);
        #pragma unroll
        for (int hh = 0; hh < 8; ++hh) a[hh] += hv * s2[hh*512 + j];
    }
    if (ok) {
        #pragma unroll
        for (int hh = 0; hh < 8; ++hh) table[hh*3969 + r] = a[hh] + fc2b[hh];
    }
}

// ---------------------------------------------------------------------------
// Materialize relative-position bias in MFMA C-fragment order, bf16.
// Layout: [h][q16 (64)][kt (16)][half (2)][lane (64)][8], 16 MB total.
// Slot (half, j): value for qrow = q16*16 + quad*4 + r, key = kt*64 + g*16 + t
// where g = half*2 + (j>>2), r = j&3, lane = quad*16 + t.
// Block = (h, q16), 4 waves; wave w does kt = w*4..w*4+3.
// ---------------------------------------------------------------------------
__global__ __launch_bounds__(256)
void bias_mat(const float* __restrict__ tblf, const int* __restrict__ rpi,
              short* __restrict__ biasM)
{
    __shared__ float tb[3969];
    int h   = blockIdx.x >> 6;
    int q16 = blockIdx.x & 63;
    int tid = threadIdx.x;
    int w = tid >> 6, lane = tid & 63, t = lane & 15, quad = lane >> 4;
    for (int i = tid; i < 3969; i += 256) tb[i] = tblf[h*3969 + i];
    __syncthreads();
    int row0 = q16*16 + quad*4;
    #pragma unroll 1
    for (int kk = 0; kk < 4; ++kk) {
        int kt = w*4 + kk;
        v8s out0, out1;
        #pragma unroll
        for (int g = 0; g < 4; ++g) {
            #pragma unroll
            for (int r = 0; r < 4; ++r) {
                int idx = rpi[(size_t)(row0 + r)*1024 + kt*64 + g*16 + t];
                short bv = f2bf(tb[idx]);
                if (g < 2) out0[g*4 + r] = bv; else out1[(g-2)*4 + r] = bv;
            }
        }
        size_t base = (((size_t)h*64 + q16)*16 + kt)*1024 + lane*8;
        *(v8s*)(biasM + base) = out0;
        *(v8s*)(biasM + base + 512) = out1;
    }
}

// ---------------------------------------------------------------------------
// Split fp32 -> bf16 hi/lo, stored 16B-chunk-swizzled for LDS-conflict-free
// frag reads: chunk c of row m stored at chunk (c ^ (m&7)) within its 64-elem
// K-tile. All arrays have inner dim K=256. x:1024 blocks, wq:96, wp:32.
// ---------------------------------------------------------------------------
__global__ __launch_bounds__(256)
void split_kernel(const float* __restrict__ x,  short* __restrict__ xh,  short* __restrict__ xl,
                  const float* __restrict__ wq, short* __restrict__ wqh, short* __restrict__ wql,
                  const float* __restrict__ wp, short* __restrict__ wph, short* __restrict__ wpl)
{
    int bid = blockIdx.x;
    const float* src; short* dh; short* dl; int base8;
    if (bid < 1024)      { src = x;  dh = xh;  dl = xl;  base8 = bid * 256; }
    else if (bid < 1120) { src = wq; dh = wqh; dl = wql; base8 = (bid-1024) * 256; }
    else                 { src = wp; dh = wph; dl = wpl; base8 = (bid-1120) * 256; }
    int e0 = (base8 + (int)threadIdx.x) * 8;
    int m  = e0 >> 8;
    int k  = e0 & 255;
    int kt = k >> 6, c = (k >> 3) & 7;
    float4 f0 = *(const float4*)(src + e0);
    float4 f1 = *(const float4*)(src + e0 + 4);
    float v[8] = {f0.x,f0.y,f0.z,f0.w,f1.x,f1.y,f1.z,f1.w};
    v8s hi, lo;
    #pragma unroll
    for (int j = 0; j < 8; ++j) {
        short h = f2bf(v[j]);
        hi[j] = h;
        lo[j] = f2bf(v[j] - bf2f(h));
    }
    int dst = m*256 + kt*64 + ((c ^ (m & 7)) << 3);
    *(v8s*)&dh[dst] = hi;
    *(v8s*)&dl[dst] = lo;
}

// ---------------------------------------------------------------------------
// Split-bf16 MFMA GEMM: C = A(MxK=256) * W(NxK=256)^T + bias, 3-pass hi/lo.
// TM=128, TN=64, BK=64, 256 threads = 4 waves (2x2 wave grid).
// MODE 0: plain fp32 C [M][N].
// MODE 1: qkv epilogue — q: l2norm + qe + softplus(temp)*ln(1024), split hi/lo;
//         k: l2norm, split hi/lo (chunk-swizzled); v: bf16 transposed to
//         vt[bh][32][1024] (64-key-tile chunk-swizzled) via LDS.
// ---------------------------------------------------------------------------
template<int MODE>
__global__ __launch_bounds__(256)
void gemm_mfma(const short* __restrict__ Ahi, const short* __restrict__ Alo,
               const short* __restrict__ Whi, const short* __restrict__ Wlo,
               const float* __restrict__ bias, float* __restrict__ C,
               short* __restrict__ qhi, short* __restrict__ qlo,
               short* __restrict__ khi, short* __restrict__ klo,
               short* __restrict__ vt,
               const float* __restrict__ qe, const float* __restrict__ temp,
               int N)
{
    __shared__ __align__(16) char smem[49152];
    short* Ah = (short*)smem;          // [128][64]
    short* Al = Ah + 128*64;
    short* Wh = Al + 128*64;           // [64][64]
    short* Wl = Wh + 64*64;

    int tid  = threadIdx.x;
    int w    = tid >> 6;
    int lane = tid & 63;
    int t    = lane & 15;
    int quad = lane >> 4;
    int m0 = blockIdx.y * 128, n0 = blockIdx.x * 64;
    int Mw = (w >> 1) * 64, Nw = (w & 1) * 32;

    v4f acc[4][2];
    #pragma unroll
    for (int mt = 0; mt < 4; ++mt)
        #pragma unroll
        for (int nt = 0; nt < 2; ++nt) acc[mt][nt] = (v4f){0,0,0,0};

    int lr8 = lane >> 3, lc8 = lane & 7;
    #pragma unroll 1
    for (int kt = 0; kt < 4; ++kt) {
        __syncthreads();
        #pragma unroll
        for (int i = 0; i < 4; ++i) {
            size_t grow = (size_t)(m0 + w*32 + i*8 + lr8) * 256 + kt*64 + lc8*8;
            int ls = (w*32 + i*8) * 64;
            gld16(Ahi + grow, Ah + ls);
            gld16(Alo + grow, Al + ls);
        }
        #pragma unroll
        for (int i = 0; i < 2; ++i) {
            size_t grow = (size_t)(n0 + w*16 + i*8 + lr8) * 256 + kt*64 + lc8*8;
            int ls = (w*16 + i*8) * 64;
            gld16(Whi + grow, Wh + ls);
            gld16(Wlo + grow, Wl + ls);
        }
        __syncthreads();
        #pragma unroll
        for (int kk = 0; kk < 2; ++kk) {
            int cp = ((kk*4 + quad) ^ (t & 7)) << 3;
            v8s bh8[2], bl8[2];
            #pragma unroll
            for (int nt = 0; nt < 2; ++nt) {
                int rowi = Nw + nt*16 + t;
                bh8[nt] = *(const v8s*)&Wh[rowi*64 + cp];
                bl8[nt] = *(const v8s*)&Wl[rowi*64 + cp];
            }
            #pragma unroll
            for (int mt = 0; mt < 4; ++mt) {
                int rowi = Mw + mt*16 + t;
                v8s ah = *(const v8s*)&Ah[rowi*64 + cp];
                v8s al = *(const v8s*)&Al[rowi*64 + cp];
                #pragma unroll
                for (int nt = 0; nt < 2; ++nt) {
                    acc[mt][nt] = MFMA(ah, bh8[nt], acc[mt][nt]);
                    acc[mt][nt] = MFMA(al, bh8[nt], acc[mt][nt]);
                    acc[mt][nt] = MFMA(ah, bl8[nt], acc[mt][nt]);
                }
            }
        }
    }

    // bias
    #pragma unroll
    for (int nt = 0; nt < 2; ++nt) {
        float bv = bias[n0 + Nw + nt*16 + t];
        #pragma unroll
        for (int mt = 0; mt < 4; ++mt)
            #pragma unroll
            for (int r = 0; r < 4; ++r) acc[mt][nt][r] += bv;
    }

    if (MODE == 0) {
        #pragma unroll
        for (int mt = 0; mt < 4; ++mt)
            #pragma unroll
            for (int r = 0; r < 4; ++r) {
                int m = m0 + Mw + mt*16 + quad*4 + r;
                #pragma unroll
                for (int nt = 0; nt < 2; ++nt) {
                    int n = n0 + Nw + nt*16 + t;
                    C[(size_t)m * N + n] = acc[mt][nt][r];
                }
            }
    } else {
        int which = n0 >> 8;                 // block-uniform (q/k/v bands are 256 wide)
        if (which < 2) {
            int head = ((n0 + Nw) >> 5) & 7; // wave-uniform
            float scale = 0.f;
            if (which == 0)
                scale = log1pf(__expf(temp[head])) * 6.9314718055994531f;
            #pragma unroll
            for (int mt = 0; mt < 4; ++mt)
                #pragma unroll
                for (int r = 0; r < 4; ++r) {
                    float a0 = acc[mt][0][r], a1 = acc[mt][1][r];
                    float s = a0*a0 + a1*a1;
                    s += __shfl_xor(s, 1); s += __shfl_xor(s, 2);
                    s += __shfl_xor(s, 4); s += __shfl_xor(s, 8);
                    float inv = 1.0f / fmaxf(sqrtf(s), 1e-12f);
                    int m = m0 + Mw + mt*16 + quad*4 + r;
                    int b = m >> 10, nrow = m & 1023;
                    size_t rowoff = (((size_t)b*8 + head)*1024 + nrow) * 32;
                    int swk = (nrow >> 1) & 3;
                    #pragma unroll
                    for (int nt = 0; nt < 2; ++nt) {
                        int d = nt*16 + t;
                        float val = acc[mt][nt][r] * inv;
                        if (which == 0) {
                            val = (val + qe[head*32 + d]) * scale;
                            short hb = f2bf(val);
                            qhi[rowoff + d] = hb;
                            qlo[rowoff + d] = f2bf(val - bf2f(hb));
                        } else {
                            int c = d >> 3;
                            int dpos = ((c ^ swk) << 3) | (d & 7);
                            short hb = f2bf(val);
                            khi[rowoff + dpos] = hb;
                            klo[rowoff + dpos] = f2bf(val - bf2f(hb));
                        }
                    }
                }
        } else {
            // v: transpose via LDS, write vt[bh][dim][key] bf16, tile-swizzled
            __syncthreads();                 // staging LDS reads done in all waves
            short* VT = (short*)smem;        // [64][136]
            #pragma unroll
            for (int mt = 0; mt < 4; ++mt)
                #pragma unroll
                for (int nt = 0; nt < 2; ++nt) {
                    int cl = Nw + nt*16 + t;
                    #pragma unroll
                    for (int r = 0; r < 4; ++r) {
                        int rl = Mw + mt*16 + quad*4 + r;
                        VT[cl*136 + rl] = f2bf(acc[mt][nt][r]);
                    }
                }
            __syncthreads();
            int b = m0 >> 10;
            int keybase = m0 & 1023;
            int headbase = ((n0 - 512) >> 5) & 7;
            int cl = tid >> 2;
            int dim = cl & 31;
            int hd  = headbase + (cl >> 5);
            size_t obase = (((size_t)b*8 + hd)*32 + dim) * 1024 + keybase;
            #pragma unroll
            for (int p = 0; p < 4; ++p) {
                int ci  = (tid & 3) * 4 + p;     // 0..15
                int ktl = ci >> 3, c = ci & 7;
                v8s val = *(const v8s*)&VT[cl*136 + ktl*64 + c*8];
                *(v8s*)&vt[obase + ktl*64 + ((c ^ (dim & 7)) << 3)] = val;
            }
        }
    }
}

// ---------------------------------------------------------------------------
// MFMA flash attention, fixed-max softmax (logits bounded by ~36 < 40).
// Block = (b,h,64-row Q tile), 4 waves x 16 Q rows. K/V staged via
// global_load_lds from pre-split/pre-swizzled khi/klo/vt. Bias loaded from
// the fragment-ordered bf16 biasM (2 coalesced v8s per lane per tile).
// Output: swizzled bf16 hi/lo y for the proj GEMM.
// ---------------------------------------------------------------------------
__global__ __launch_bounds__(256)
void attn_mfma(const short* __restrict__ qhi, const short* __restrict__ qlo,
               const short* __restrict__ khi, const short* __restrict__ klo,
               const short* __restrict__ vt,  const short* __restrict__ biasM,
               short* __restrict__ yhi, short* __restrict__ ylo)
{
    __shared__ __align__(16) short Khi_s[2048];   // [64][32]
    __shared__ __align__(16) short Klo_s[2048];
    __shared__ __align__(16) short Vt_s[2048];    // [32][64]
    __shared__ __align__(16) short Ps[4][16][68]; // per-wave P

    int bh  = blockIdx.x >> 4;
    int qt  = blockIdx.x & 15;
    int h   = bh & 7;
    int b   = bh >> 3;
    int tid = threadIdx.x;
    int w    = tid >> 6;
    int lane = tid & 63;
    int t    = lane & 15;
    int quad = lane >> 4;

    // Q fragments from global (plain layout)
    size_t qoff = ((size_t)bh*1024 + qt*64 + w*16 + t) * 32 + quad*8;
    v8s qfh = *(const v8s*)(qhi + qoff);
    v8s qfl = *(const v8s*)(qlo + qoff);

    v4f Oacc[2] = {{0,0,0,0},{0,0,0,0}};
    float lsum[4] = {0,0,0,0};

    size_t kgbase = (size_t)bh * 32768;
    const short* bmbase = biasM + (((size_t)h*64 + qt*4 + w)*16)*1024 + lane*8;
    int qrow0 = qt*64 + w*16 + quad*4;
    int swzS = (quad ^ ((t >> 1) & 3)) << 3;
    int lr8 = lane >> 3, lc8 = lane & 7;

    #pragma unroll 1
    for (int kt = 0; kt < 16; ++kt) {
        __syncthreads();
        // stage K hi/lo (64x32) and V^T (32x64): 3 async 1KB loads per wave
        gld16(khi + kgbase + (size_t)kt*2048 + w*512 + lane*8, &Khi_s[w*512]);
        gld16(klo + kgbase + (size_t)kt*2048 + w*512 + lane*8, &Klo_s[w*512]);
        gld16(vt + kgbase + (size_t)(w*8 + lr8)*1024 + kt*64 + lc8*8, &Vt_s[w*512]);
        // bias fragments for this tile (coalesced, L2/L3-resident)
        const short* bp = bmbase + (size_t)kt*1024;
        v8s bb0 = *(const v8s*)bp;          // g0,g1
        v8s bb1 = *(const v8s*)(bp + 512);  // g2,g3
        __syncthreads();

        // S = Q K^T, split-bf16 3 passes
        v4f S[4];
        #pragma unroll
        for (int g = 0; g < 4; ++g) {
            const short* kb  = &Khi_s[(g*16 + t)*32];
            const short* kl2 = &Klo_s[(g*16 + t)*32];
            v8s bh8 = *(const v8s*)(kb + swzS);
            v8s bl8 = *(const v8s*)(kl2 + swzS);
            v4f c = {0,0,0,0};
            c = MFMA(qfh, bh8, c);
            c = MFMA(qfl, bh8, c);
            c = MFMA(qfh, bl8, c);
            S[g] = c;
        }

        // fixed-max softmax with fused bias: p = exp(S + bias - 40)
        #pragma unroll
        for (int r = 0; r < 4; ++r) {
            int prow = quad*4 + r;
            #pragma unroll
            for (int g = 0; g < 4; ++g) {
                short bs = (g < 2) ? bb0[g*4 + r] : bb1[(g-2)*4 + r];
                float p = __expf(S[g][r] + bf2f(bs) - 40.0f);
                lsum[r] += p;
                Ps[w][prow][g*16 + t] = f2bf(p);
            }
        }
        // O += P V (per-wave LDS, same-wave dependency)
        #pragma unroll
        for (int ks = 0; ks < 2; ++ks) {
            v8s pf = *(const v8s*)&Ps[w][t][ks*32 + quad*8];
            int vsw = ((ks*4 + quad) ^ (t & 7)) << 3;
            #pragma unroll
            for (int g = 0; g < 2; ++g) {
                v8s vf = *(const v8s*)(&Vt_s[(g*16 + t)*64] + vsw);
                Oacc[g] = MFMA(pf, vf, Oacc[g]);
            }
        }
    }

    // epilogue: reduce l across the 16 key-lanes, normalize, write swizzled y
    #pragma unroll
    for (int r = 0; r < 4; ++r) {
        float l = lsum[r];
        l += __shfl_xor(l, 1); l += __shfl_xor(l, 2);
        l += __shfl_xor(l, 4); l += __shfl_xor(l, 8);
        float inv = 1.0f / l;
        int qrow = qrow0 + r;
        int m = b*1024 + qrow;
        size_t mbase = (size_t)m * 256;
        int mk = m & 7;
        #pragma unroll
        for (int g = 0; g < 2; ++g) {
            float o = Oacc[g][r] * inv;
            int c = h*4 + g*2 + (t >> 3);
            int chp = ((c ^ mk) << 3) | (t & 7);
            short hb = f2bf(o);
            yhi[mbase + chp] = hb;
            ylo[mbase + chp] = f2bf(o - bf2f(hb));
        }
    }
}

// ---------------------------------------------------------------------------
extern "C" void kernel_launch(void* const* d_in, const int* in_sizes, int n_in,
                              void* d_out, int out_size, void* d_ws, size_t ws_size,
                              hipStream_t stream)
{
    const float* x     = (const float*)d_in[0];
    const int*   rpi   = (const int*)d_in[3];
    const float* rct   = (const float*)d_in[4];
    const float* qkvw  = (const float*)d_in[5];
    const float* qkvb  = (const float*)d_in[6];
    const float* qe    = (const float*)d_in[7];
    const float* temp  = (const float*)d_in[8];
    const float* projw = (const float*)d_in[9];
    const float* projb = (const float*)d_in[10];
    const float* fc1w  = (const float*)d_in[11];
    const float* fc1b  = (const float*)d_in[12];
    const float* fc2w  = (const float*)d_in[13];
    const float* fc2b  = (const float*)d_in[14];

    char* p = (char*)d_ws;
    float* tblf  = (float*)p;  p += 131072;
    short* xh    = (short*)p;  p += 4194304;   // reused as yhi after QKV GEMM
    short* xl    = (short*)p;  p += 4194304;   // reused as ylo
    short* wqh   = (short*)p;  p += 393216;
    short* wql   = (short*)p;  p += 393216;
    short* wph   = (short*)p;  p += 131072;
    short* wpl   = (short*)p;  p += 131072;
    short* qh    = (short*)p;  p += 4194304;
    short* ql    = (short*)p;  p += 4194304;
    short* kh    = (short*)p;  p += 4194304;
    short* kl    = (short*)p;  p += 4194304;
    short* vt    = (short*)p;  p += 4194304;
    short* biasM = (short*)p;  p += 16777216;
    float* out   = (float*)d_out;

    // 1) CPB MLP -> fp32 bias table [8][3969]
    cpb_kernel<<<16, 256, 0, stream>>>(rct, fc1w, fc1b, fc2w, fc2b, tblf);

    // 2) materialize fragment-ordered bf16 bias (batch-independent, done once)
    bias_mat<<<512, 256, 0, stream>>>(tblf, rpi, biasM);

    // 3) split x / qkv_w / proj_w into swizzled bf16 hi/lo
    split_kernel<<<1152, 256, 0, stream>>>(x, xh, xl, qkvw, wqh, wql, projw, wph, wpl);

    // 4) QKV GEMM + fused l2norm/scale/split + V transpose
    dim3 g1(768/64, 8192/128);
    gemm_mfma<1><<<g1, 256, 0, stream>>>(xh, xl, wqh, wql, qkvb, nullptr,
                                         qh, ql, kh, kl, vt, qe, temp, 768);

    // 5) MFMA attention -> swizzled bf16 hi/lo y (aliases xh/xl)
    attn_mfma<<<1024, 256, 0, stream>>>(qh, ql, kh, kl, vt, biasM, xh, xl);

    // 6) output projection -> d_out (fp32)
    dim3 g2(256/64, 8192/128);
    gemm_mfma<0><<<g2, 256, 0, stream>>>(xh, xl, wph, wpl, projb, out,
                                         nullptr, nullptr, nullptr, nullptr,
                                         nullptr, nullptr, nullptr, 256);
}

// Round 5
// 170.290 us; speedup vs baseline: 1.1638x; 1.1638x over previous
//
#include <hip/hip_runtime.h>
#include <hip/hip_bf16.h>
#include <cstddef>
#include <cstdint>

typedef float v4f __attribute__((ext_vector_type(4)));
typedef short v8s __attribute__((ext_vector_type(8)));

__device__ __forceinline__ short f2bf(float x) {
    __hip_bfloat16 h = __float2bfloat16(x);
    short s; __builtin_memcpy(&s, &h, 2); return s;
}
__device__ __forceinline__ float bf2f(short s) {
    __hip_bfloat16 h; __builtin_memcpy(&h, &s, 2);
    return __bfloat162float(h);
}
__device__ __forceinline__ void gld16(const void* g, void* l) {
    __builtin_amdgcn_global_load_lds(
        (const __attribute__((address_space(1))) unsigned int*)g,
        (__attribute__((address_space(3))) unsigned int*)l, 16, 0, 0);
}
#define MFMA(a,b,c) __builtin_amdgcn_mfma_f32_16x16x32_bf16((a),(b),(c),0,0,0)

// ---------------------------------------------------------------------------
// CPB MLP, parallelized over hidden-dim chunks: grid (16 row-blocks, 8 j-chunks)
// table must be pre-zeroed; partials accumulated with atomicAdd.
// ---------------------------------------------------------------------------
__global__ __launch_bounds__(256)
void cpb_kernel(const float* __restrict__ rct,
                const float* __restrict__ fc1w, const float* __restrict__ fc1b,
                const float* __restrict__ fc2w, const float* __restrict__ fc2b,
                float* __restrict__ table)
{
    __shared__ float s1[128];
    __shared__ float sb[64];
    __shared__ float s2[8][64];
    int tid = threadIdx.x;
    int jc  = blockIdx.y;
    int j0  = jc * 64;
    if (tid < 128) s1[tid] = fc1w[j0*2 + tid];
    else if (tid < 192) sb[tid-128] = fc1b[j0 + tid - 128];
    for (int i = tid; i < 512; i += 256) s2[i >> 6][i & 63] = fc2w[(i>>6)*512 + j0 + (i & 63)];
    __syncthreads();
    int r = blockIdx.x * 256 + tid;
    bool ok = r < 3969;
    float c0 = ok ? rct[2*r]   : 0.f;
    float c1 = ok ? rct[2*r+1] : 0.f;
    float a[8] = {0,0,0,0,0,0,0,0};
    #pragma unroll 4
    for (int j = 0; j < 64; ++j) {
        float hv = fmaxf(c0*s1[2*j] + c1*s1[2*j+1] + sb[j], 0.0f);
        #pragma unroll
        for (int hh = 0; hh < 8; ++hh) a[hh] += hv * s2[hh][j];
    }
    if (ok) {
        #pragma unroll
        for (int hh = 0; hh < 8; ++hh)
            atomicAdd(&table[hh*3969 + r], a[hh] + (jc == 0 ? fc2b[hh] : 0.f));
    }
}

// ---------------------------------------------------------------------------
// Materialize relative-position bias as fp32, MFMA-C-fragment order, with the
// fixed softmax max (40) pre-subtracted. Key order matches the permuted K
// staging: S-MFMA group g, col-lane t covers actual key kt*64 + 4t + g.
// Layout: [h][q16(64)][kt(16)][g(4)][lane(64)][r(4)] fp32 = 32 MB.
// ---------------------------------------------------------------------------
__global__ __launch_bounds__(256)
void bias_mat(const float* __restrict__ tblf, const int* __restrict__ rpi,
              float* __restrict__ biasM)
{
    __shared__ float tb[3969];
    int h   = blockIdx.x >> 6;
    int q16 = blockIdx.x & 63;
    int tid = threadIdx.x;
    int w = tid >> 6, lane = tid & 63, t = lane & 15, quad = lane >> 4;
    for (int i = tid; i < 3969; i += 256) tb[i] = tblf[h*3969 + i];
    __syncthreads();
    int row0 = q16*16 + quad*4;
    #pragma unroll 1
    for (int kk = 0; kk < 4; ++kk) {
        int kt = w*4 + kk;
        #pragma unroll
        for (int g = 0; g < 4; ++g) {
            v4f o;
            #pragma unroll
            for (int r = 0; r < 4; ++r) {
                int idx = rpi[(size_t)(row0 + r)*1024 + kt*64 + 4*t + g];
                o[r] = tb[idx] - 40.0f;
            }
            size_t base = ((((size_t)(h*64 + q16)*16 + kt)*4 + g)*64 + lane)*4;
            *(v4f*)(biasM + base) = o;
        }
    }
}

// ---------------------------------------------------------------------------
// Split fp32 -> bf16 hi/lo, 16B-chunk-swizzled: chunk c of row m stored at
// chunk (c ^ (m&7)) within its 64-elem K-tile. Inner dim K=256.
// ---------------------------------------------------------------------------
__global__ __launch_bounds__(256)
void split_kernel(const float* __restrict__ x,  short* __restrict__ xh,  short* __restrict__ xl,
                  const float* __restrict__ wq, short* __restrict__ wqh, short* __restrict__ wql,
                  const float* __restrict__ wp, short* __restrict__ wph, short* __restrict__ wpl)
{
    int bid = blockIdx.x;
    const float* src; short* dh; short* dl; int base8;
    if (bid < 1024)      { src = x;  dh = xh;  dl = xl;  base8 = bid * 256; }
    else if (bid < 1120) { src = wq; dh = wqh; dl = wql; base8 = (bid-1024) * 256; }
    else                 { src = wp; dh = wph; dl = wpl; base8 = (bid-1120) * 256; }
    int e0 = (base8 + (int)threadIdx.x) * 8;
    int m  = e0 >> 8;
    int k  = e0 & 255;
    int kt = k >> 6, c = (k >> 3) & 7;
    float4 f0 = *(const float4*)(src + e0);
    float4 f1 = *(const float4*)(src + e0 + 4);
    float v[8] = {f0.x,f0.y,f0.z,f0.w,f1.x,f1.y,f1.z,f1.w};
    v8s hi, lo;
    #pragma unroll
    for (int j = 0; j < 8; ++j) {
        short h = f2bf(v[j]);
        hi[j] = h;
        lo[j] = f2bf(v[j] - bf2f(h));
    }
    int dst = m*256 + kt*64 + ((c ^ (m & 7)) << 3);
    *(v8s*)&dh[dst] = hi;
    *(v8s*)&dl[dst] = lo;
}

// ---------------------------------------------------------------------------
// Split-bf16 MFMA GEMM: C = A(MxK=256) * W(NxK=256)^T + bias.
// PASSES=3: hi*hi + lo*hi + hi*lo (fp32-grade). PASSES=1: hi*hi only.
// MODE 1 (qkv): v band (n0>=512) runs 1-pass; q/k bands 3-pass. Epilogue:
//   q: l2norm + qe + softplus(temp)*ln(1024), plain hi/lo;
//   k: l2norm, hi/lo stored KEY-PERMUTED within 64-tiles (pos p holds key
//      (p&15)*4 + (p>>4)) and chunk-swizzled for the attn frag reads;
//   v: bf16 transposed to vt[bh][32][1024] (chunk-swizzled) via LDS.
// MODE 0: plain fp32 C [M][N].
// ---------------------------------------------------------------------------
template<int MODE, int PASSES>
__global__ __launch_bounds__(256)
void gemm_mfma(const short* __restrict__ Ahi, const short* __restrict__ Alo,
               const short* __restrict__ Whi, const short* __restrict__ Wlo,
               const float* __restrict__ bias, float* __restrict__ C,
               short* __restrict__ qhi, short* __restrict__ qlo,
               short* __restrict__ khi, short* __restrict__ klo,
               short* __restrict__ vt,
               const float* __restrict__ qe, const float* __restrict__ temp,
               int N)
{
    __shared__ __align__(16) char smem[49152];
    short* Ah = (short*)smem;          // [128][64]
    short* Al = Ah + 128*64;
    short* Wh = Al + 128*64;           // [64][64]
    short* Wl = Wh + 64*64;

    int tid  = threadIdx.x;
    int w    = tid >> 6;
    int lane = tid & 63;
    int t    = lane & 15;
    int quad = lane >> 4;
    int m0 = blockIdx.y * 128, n0 = blockIdx.x * 64;
    int Mw = (w >> 1) * 64, Nw = (w & 1) * 32;
    const bool onep = (PASSES == 1) || (MODE == 1 && n0 >= 512);

    v4f acc[4][2];
    #pragma unroll
    for (int mt = 0; mt < 4; ++mt)
        #pragma unroll
        for (int nt = 0; nt < 2; ++nt) acc[mt][nt] = (v4f){0,0,0,0};

    int lr8 = lane >> 3, lc8 = lane & 7;
    #pragma unroll 1
    for (int kt = 0; kt < 4; ++kt) {
        __syncthreads();
        #pragma unroll
        for (int i = 0; i < 4; ++i) {
            size_t grow = (size_t)(m0 + w*32 + i*8 + lr8) * 256 + kt*64 + lc8*8;
            int ls = (w*32 + i*8) * 64;
            gld16(Ahi + grow, Ah + ls);
            if (!onep) gld16(Alo + grow, Al + ls);
        }
        #pragma unroll
        for (int i = 0; i < 2; ++i) {
            size_t grow = (size_t)(n0 + w*16 + i*8 + lr8) * 256 + kt*64 + lc8*8;
            int ls = (w*16 + i*8) * 64;
            gld16(Whi + grow, Wh + ls);
            if (!onep) gld16(Wlo + grow, Wl + ls);
        }
        __syncthreads();
        #pragma unroll
        for (int kk = 0; kk < 2; ++kk) {
            int cp = ((kk*4 + quad) ^ (t & 7)) << 3;
            v8s bh8[2], bl8[2];
            #pragma unroll
            for (int nt = 0; nt < 2; ++nt) {
                int rowi = Nw + nt*16 + t;
                bh8[nt] = *(const v8s*)&Wh[rowi*64 + cp];
                if (!onep) bl8[nt] = *(const v8s*)&Wl[rowi*64 + cp];
            }
            #pragma unroll
            for (int mt = 0; mt < 4; ++mt) {
                int rowi = Mw + mt*16 + t;
                v8s ah = *(const v8s*)&Ah[rowi*64 + cp];
                v8s al;
                if (!onep) al = *(const v8s*)&Al[rowi*64 + cp];
                #pragma unroll
                for (int nt = 0; nt < 2; ++nt) {
                    acc[mt][nt] = MFMA(ah, bh8[nt], acc[mt][nt]);
                    if (!onep) {
                        acc[mt][nt] = MFMA(al, bh8[nt], acc[mt][nt]);
                        acc[mt][nt] = MFMA(ah, bl8[nt], acc[mt][nt]);
                    }
                }
            }
        }
    }

    // bias
    #pragma unroll
    for (int nt = 0; nt < 2; ++nt) {
        float bv = bias[n0 + Nw + nt*16 + t];
        #pragma unroll
        for (int mt = 0; mt < 4; ++mt)
            #pragma unroll
            for (int r = 0; r < 4; ++r) acc[mt][nt][r] += bv;
    }

    if (MODE == 0) {
        #pragma unroll
        for (int mt = 0; mt < 4; ++mt)
            #pragma unroll
            for (int r = 0; r < 4; ++r) {
                int m = m0 + Mw + mt*16 + quad*4 + r;
                #pragma unroll
                for (int nt = 0; nt < 2; ++nt) {
                    int n = n0 + Nw + nt*16 + t;
                    C[(size_t)m * N + n] = acc[mt][nt][r];
                }
            }
    } else {
        int which = n0 >> 8;
        if (which < 2) {
            int head = ((n0 + Nw) >> 5) & 7;
            float scale = 0.f;
            if (which == 0)
                scale = log1pf(__expf(temp[head])) * 6.9314718055994531f;
            #pragma unroll
            for (int mt = 0; mt < 4; ++mt)
                #pragma unroll
                for (int r = 0; r < 4; ++r) {
                    float a0 = acc[mt][0][r], a1 = acc[mt][1][r];
                    float s = a0*a0 + a1*a1;
                    s += __shfl_xor(s, 1); s += __shfl_xor(s, 2);
                    s += __shfl_xor(s, 4); s += __shfl_xor(s, 8);
                    float inv = 1.0f / fmaxf(sqrtf(s), 1e-12f);
                    int m = m0 + Mw + mt*16 + quad*4 + r;
                    int b = m >> 10, nrow = m & 1023;
                    if (which == 0) {
                        size_t rowoff = (((size_t)b*8 + head)*1024 + nrow) * 32;
                        #pragma unroll
                        for (int nt = 0; nt < 2; ++nt) {
                            int d = nt*16 + t;
                            float val = (acc[mt][nt][r] * inv + qe[head*32 + d]) * scale;
                            short hb = f2bf(val);
                            qhi[rowoff + d] = hb;
                            qlo[rowoff + d] = f2bf(val - bf2f(hb));
                        }
                    } else {
                        // key-permuted position within 64-tile + chunk swizzle
                        int kk = nrow & 63;
                        int p  = (kk & 3)*16 + (kk >> 2);
                        int prow = (nrow & ~63) | p;
                        int swk = (kk >> 3) & 3;
                        size_t rowoff = (((size_t)b*8 + head)*1024 + prow) * 32;
                        #pragma unroll
                        for (int nt = 0; nt < 2; ++nt) {
                            int d = nt*16 + t;
                            int c = d >> 3;
                            int dpos = ((c ^ swk) << 3) | (d & 7);
                            float val = acc[mt][nt][r] * inv;
                            short hb = f2bf(val);
                            khi[rowoff + dpos] = hb;
                            klo[rowoff + dpos] = f2bf(val - bf2f(hb));
                        }
                    }
                }
        } else {
            // v: transpose via LDS, write vt[bh][dim][key] bf16, tile-swizzled
            __syncthreads();
            short* VT = (short*)smem;        // [64][136]
            #pragma unroll
            for (int mt = 0; mt < 4; ++mt)
                #pragma unroll
                for (int nt = 0; nt < 2; ++nt) {
                    int cl = Nw + nt*16 + t;
                    #pragma unroll
                    for (int r = 0; r < 4; ++r) {
                        int rl = Mw + mt*16 + quad*4 + r;
                        VT[cl*136 + rl] = f2bf(acc[mt][nt][r]);
                    }
                }
            __syncthreads();
            int b = m0 >> 10;
            int keybase = m0 & 1023;
            int headbase = ((n0 - 512) >> 5) & 7;
            int cl = tid >> 2;
            int dim = cl & 31;
            int hd  = headbase + (cl >> 5);
            size_t obase = (((size_t)b*8 + hd)*32 + dim) * 1024 + keybase;
            #pragma unroll
            for (int p = 0; p < 4; ++p) {
                int ci  = (tid & 3) * 4 + p;
                int ktl = ci >> 3, c = ci & 7;
                v8s val = *(const v8s*)&VT[cl*136 + ktl*64 + c*8];
                *(v8s*)&vt[obase + ktl*64 + ((c ^ (dim & 7)) << 3)] = val;
            }
        }
    }
}

// ---------------------------------------------------------------------------
// MFMA flash attention, fixed-max softmax, double-buffered K/V LDS (1 barrier
// per tile, staging overlaps compute), fp32 bias as MFMA C-init (max folded),
// key-permuted K so P stores are contiguous b64 writes. Output: swizzled bf16
// y (hi only — proj GEMM is 1-pass).
// ---------------------------------------------------------------------------
__global__ __launch_bounds__(256)
void attn_mfma(const short* __restrict__ qhi, const short* __restrict__ qlo,
               const short* __restrict__ khi, const short* __restrict__ klo,
               const short* __restrict__ vt,  const float* __restrict__ biasM,
               short* __restrict__ yhi)
{
    __shared__ __align__(16) short Khi_s[2][2048];   // [64][32]
    __shared__ __align__(16) short Klo_s[2][2048];
    __shared__ __align__(16) short Vt_s[2][2048];    // [32][64]
    __shared__ __align__(16) short Ps[4][16][68];    // per-wave P (cols=keys)

    int bh  = blockIdx.x >> 4;
    int qt  = blockIdx.x & 15;
    int h   = bh & 7;
    int b   = bh >> 3;
    int tid = threadIdx.x;
    int w    = tid >> 6;
    int lane = tid & 63;
    int t    = lane & 15;
    int quad = lane >> 4;

    size_t qoff = ((size_t)bh*1024 + qt*64 + w*16 + t) * 32 + quad*8;
    v8s qfh = *(const v8s*)(qhi + qoff);
    v8s qfl = *(const v8s*)(qlo + qoff);

    v4f Oacc[2] = {{0,0,0,0},{0,0,0,0}};
    float lsum[4] = {0,0,0,0};

    size_t kgbase = (size_t)bh * 32768;
    const float* bmb = biasM + ((size_t)(h*64 + qt*4 + w) * 16) * 1024 + lane*4;
    int qrow0 = qt*64 + w*16 + quad*4;
    int swzS = (quad ^ ((t >> 1) & 3)) << 3;
    int lr8 = lane >> 3, lc8 = lane & 7;

    // stage tile 0 into buffer 0
    gld16(khi + kgbase + w*512 + lane*8, &Khi_s[0][w*512]);
    gld16(klo + kgbase + w*512 + lane*8, &Klo_s[0][w*512]);
    gld16(vt + kgbase + (size_t)(w*8 + lr8)*1024 + lc8*8, &Vt_s[0][w*512]);
    // bias for tile 0 (registers, software-pipelined)
    v4f curb[4];
    #pragma unroll
    for (int g = 0; g < 4; ++g) curb[g] = *(const v4f*)(bmb + g*256);

    #pragma unroll 1
    for (int kt = 0; kt < 16; ++kt) {
        int cur = kt & 1;
        __syncthreads();   // prior reads of nxt done; cur's staged writes landed
        v4f nxtb[4];
        if (kt < 15) {
            int nkt = kt + 1, nb = cur ^ 1;
            gld16(khi + kgbase + (size_t)nkt*2048 + w*512 + lane*8, &Khi_s[nb][w*512]);
            gld16(klo + kgbase + (size_t)nkt*2048 + w*512 + lane*8, &Klo_s[nb][w*512]);
            gld16(vt + kgbase + (size_t)(w*8 + lr8)*1024 + nkt*64 + lc8*8, &Vt_s[nb][w*512]);
            const float* bp = bmb + (size_t)nkt*1024;
            #pragma unroll
            for (int g = 0; g < 4; ++g) nxtb[g] = *(const v4f*)(bp + g*256);
        }

        // S = bias - 40 + Q K^T (split-bf16, 3 passes)
        v4f S[4];
        #pragma unroll
        for (int g = 0; g < 4; ++g) {
            v8s bh8 = *(const v8s*)&Khi_s[cur][(g*16 + t)*32 + swzS];
            v8s bl8 = *(const v8s*)&Klo_s[cur][(g*16 + t)*32 + swzS];
            v4f c = curb[g];
            c = MFMA(qfh, bh8, c);
            c = MFMA(qfl, bh8, c);
            c = MFMA(qfh, bl8, c);
            S[g] = c;
        }

        // p = exp(S); P cols are contiguous actual keys 4t+g -> one b64/row
        #pragma unroll
        for (int r = 0; r < 4; ++r) {
            float p0 = __expf(S[0][r]);
            float p1 = __expf(S[1][r]);
            float p2 = __expf(S[2][r]);
            float p3 = __expf(S[3][r]);
            lsum[r] += (p0 + p1) + (p2 + p3);
            uint2 pk;
            pk.x = (uint32_t)(uint16_t)f2bf(p0) | ((uint32_t)(uint16_t)f2bf(p1) << 16);
            pk.y = (uint32_t)(uint16_t)f2bf(p2) | ((uint32_t)(uint16_t)f2bf(p3) << 16);
            *(uint2*)&Ps[w][quad*4 + r][t*4] = pk;
        }

        // O += P V (same-wave LDS dependency, no barrier)
        #pragma unroll
        for (int ks = 0; ks < 2; ++ks) {
            v8s pf = *(const v8s*)&Ps[w][t][ks*32 + quad*8];
            int vsw = ((ks*4 + quad) ^ (t & 7)) << 3;
            #pragma unroll
            for (int g = 0; g < 2; ++g) {
                v8s vf = *(const v8s*)&Vt_s[cur][(g*16 + t)*64 + vsw];
                Oacc[g] = MFMA(pf, vf, Oacc[g]);
            }
        }
        #pragma unroll
        for (int g = 0; g < 4; ++g) curb[g] = nxtb[g];
    }

    // epilogue: reduce l, normalize, write swizzled bf16 y (hi only)
    #pragma unroll
    for (int r = 0; r < 4; ++r) {
        float l = lsum[r];
        l += __shfl_xor(l, 1); l += __shfl_xor(l, 2);
        l += __shfl_xor(l, 4); l += __shfl_xor(l, 8);
        float inv = 1.0f / l;
        int qrow = qrow0 + r;
        int m = b*1024 + qrow;
        size_t mbase = (size_t)m * 256;
        int mk = m & 7;
        #pragma unroll
        for (int g = 0; g < 2; ++g) {
            float o = Oacc[g][r] * inv;
            int c = h*4 + g*2 + (t >> 3);
            int chp = ((c ^ mk) << 3) | (t & 7);
            yhi[mbase + chp] = f2bf(o);
        }
    }
}

// ---------------------------------------------------------------------------
extern "C" void kernel_launch(void* const* d_in, const int* in_sizes, int n_in,
                              void* d_out, int out_size, void* d_ws, size_t ws_size,
                              hipStream_t stream)
{
    const float* x     = (const float*)d_in[0];
    const int*   rpi   = (const int*)d_in[3];
    const float* rct   = (const float*)d_in[4];
    const float* qkvw  = (const float*)d_in[5];
    const float* qkvb  = (const float*)d_in[6];
    const float* qe    = (const float*)d_in[7];
    const float* temp  = (const float*)d_in[8];
    const float* projw = (const float*)d_in[9];
    const float* projb = (const float*)d_in[10];
    const float* fc1w  = (const float*)d_in[11];
    const float* fc1b  = (const float*)d_in[12];
    const float* fc2w  = (const float*)d_in[13];
    const float* fc2b  = (const float*)d_in[14];

    char* p = (char*)d_ws;
    float* tblf  = (float*)p;  p += 131072;
    short* xh    = (short*)p;  p += 4194304;   // reused as yhi after QKV GEMM
    short* xl    = (short*)p;  p += 4194304;
    short* wqh   = (short*)p;  p += 393216;
    short* wql   = (short*)p;  p += 393216;
    short* wph   = (short*)p;  p += 131072;
    short* wpl   = (short*)p;  p += 131072;
    short* qh    = (short*)p;  p += 4194304;
    short* ql    = (short*)p;  p += 4194304;
    short* kh    = (short*)p;  p += 4194304;
    short* kl    = (short*)p;  p += 4194304;
    short* vt    = (short*)p;  p += 4194304;
    float* biasM = (float*)p;  p += 33554432;
    float* out   = (float*)d_out;

    // 1) zero the cpb accumulator, then CPB MLP (parallel over j-chunks)
    hipMemsetAsync(tblf, 0, 8*3969*sizeof(float), stream);
    cpb_kernel<<<dim3(16,8), 256, 0, stream>>>(rct, fc1w, fc1b, fc2w, fc2b, tblf);

    // 2) fragment-ordered fp32 bias with -40 folded (batch-independent)
    bias_mat<<<512, 256, 0, stream>>>(tblf, rpi, biasM);

    // 3) split x / qkv_w / proj_w into swizzled bf16 hi/lo
    split_kernel<<<1152, 256, 0, stream>>>(x, xh, xl, qkvw, wqh, wql, projw, wph, wpl);

    // 4) QKV GEMM + fused l2norm/scale/split + V transpose (v band 1-pass)
    dim3 g1(768/64, 8192/128);
    gemm_mfma<1,3><<<g1, 256, 0, stream>>>(xh, xl, wqh, wql, qkvb, nullptr,
                                           qh, ql, kh, kl, vt, qe, temp, 768);

    // 5) MFMA attention -> swizzled bf16 y (aliases xh)
    attn_mfma<<<1024, 256, 0, stream>>>(qh, ql, kh, kl, vt, biasM, xh);

    // 6) output projection (1-pass bf16) -> d_out (fp32)
    dim3 g2(256/64, 8192/128);
    gemm_mfma<0,1><<<g2, 256, 0, stream>>>(xh, nullptr, wph, nullptr, projb, out,
                                           nullptr, nullptr, nullptr, nullptr,
                                           nullptr, nullptr, nullptr, 256);
}

// Round 6
// 169.192 us; speedup vs baseline: 1.1714x; 1.0065x over previous
//
#include <hip/hip_runtime.h>
#include <hip/hip_bf16.h>
#include <cstddef>
#include <cstdint>

typedef float v4f __attribute__((ext_vector_type(4)));
typedef short v8s __attribute__((ext_vector_type(8)));

__device__ __forceinline__ uint32_t fbits(float x){ uint32_t u; __builtin_memcpy(&u,&x,4); return u; }
__device__ __forceinline__ float ffrom(uint32_t u){ float f; __builtin_memcpy(&f,&u,4); return f; }
// round-half-up bf16 (error bound = RNE except ties; no NaN path needed here)
__device__ __forceinline__ short bf_rh(float x){ return (short)((fbits(x)+0x8000u)>>16); }
// pack bf16(a) into low short, bf16(b) into high short
__device__ __forceinline__ uint32_t pack_bf_rh(float a, float b){
    uint32_t ua = fbits(a)+0x8000u, ub = fbits(b)+0x8000u;
#if __has_builtin(__builtin_amdgcn_perm)
    return __builtin_amdgcn_perm(ub, ua, 0x07060302u);
#else
    return (ua>>16) | (ub & 0xFFFF0000u);
#endif
}
#if __has_builtin(__builtin_amdgcn_exp2f)
#define EXP2(x) __builtin_amdgcn_exp2f(x)
#else
#define EXP2(x) exp2f(x)
#endif

__device__ __forceinline__ void gld16(const void* g, void* l) {
    __builtin_amdgcn_global_load_lds(
        (const __attribute__((address_space(1))) unsigned int*)g,
        (__attribute__((address_space(3))) unsigned int*)l, 16, 0, 0);
}
#define MFMA(a,b,c) __builtin_amdgcn_mfma_f32_16x16x32_bf16((a),(b),(c),0,0,0)

#define LOG2E 1.4426950408889634f

// ---------------------------------------------------------------------------
// CPB MLP, parallelized over hidden-dim chunks: grid (16 row-blocks, 8 j-chunks)
// table must be pre-zeroed; partials accumulated with atomicAdd.
// ---------------------------------------------------------------------------
__global__ __launch_bounds__(256)
void cpb_kernel(const float* __restrict__ rct,
                const float* __restrict__ fc1w, const float* __restrict__ fc1b,
                const float* __restrict__ fc2w, const float* __restrict__ fc2b,
                float* __restrict__ table)
{
    __shared__ float s1[128];
    __shared__ float sb[64];
    __shared__ float s2[8][64];
    int tid = threadIdx.x;
    int jc  = blockIdx.y;
    int j0  = jc * 64;
    if (tid < 128) s1[tid] = fc1w[j0*2 + tid];
    else if (tid < 192) sb[tid-128] = fc1b[j0 + tid - 128];
    for (int i = tid; i < 512; i += 256) s2[i >> 6][i & 63] = fc2w[(i>>6)*512 + j0 + (i & 63)];
    __syncthreads();
    int r = blockIdx.x * 256 + tid;
    bool ok = r < 3969;
    float c0 = ok ? rct[2*r]   : 0.f;
    float c1 = ok ? rct[2*r+1] : 0.f;
    float a[8] = {0,0,0,0,0,0,0,0};
    #pragma unroll 4
    for (int j = 0; j < 64; ++j) {
        float hv = fmaxf(c0*s1[2*j] + c1*s1[2*j+1] + sb[j], 0.0f);
        #pragma unroll
        for (int hh = 0; hh < 8; ++hh) a[hh] += hv * s2[hh][j];
    }
    if (ok) {
        #pragma unroll
        for (int hh = 0; hh < 8; ++hh)
            atomicAdd(&table[hh*3969 + r], a[hh] + (jc == 0 ? fc2b[hh] : 0.f));
    }
}

// ---------------------------------------------------------------------------
// Materialize relative-position bias as bf16, scaled by log2(e), in MFMA
// C-fragment order matching the permuted K staging (key kt*64 + 4t + g).
// Layout: [h][q16(64)][kt(16)][g(4)][lane(64)][4 shorts] = 16 MB.
// ---------------------------------------------------------------------------
__global__ __launch_bounds__(256)
void bias_mat(const float* __restrict__ tblf, const int* __restrict__ rpi,
              short* __restrict__ biasM)
{
    __shared__ float tb[3969];
    int h   = blockIdx.x >> 6;
    int q16 = blockIdx.x & 63;
    int tid = threadIdx.x;
    int w = tid >> 6, lane = tid & 63, t = lane & 15, quad = lane >> 4;
    for (int i = tid; i < 3969; i += 256) tb[i] = tblf[h*3969 + i] * LOG2E;
    __syncthreads();
    int row0 = q16*16 + quad*4;
    #pragma unroll 1
    for (int kk = 0; kk < 4; ++kk) {
        int kt = w*4 + kk;
        #pragma unroll
        for (int g = 0; g < 4; ++g) {
            float o[4];
            #pragma unroll
            for (int r = 0; r < 4; ++r)
                o[r] = tb[rpi[(size_t)(row0 + r)*1024 + kt*64 + 4*t + g]];
            uint2 pk;
            pk.x = pack_bf_rh(o[0], o[1]);
            pk.y = pack_bf_rh(o[2], o[3]);
            size_t base = ((((size_t)(h*64 + q16)*16 + kt)*4 + g)*64 + lane)*4;
            *(uint2*)(biasM + base) = pk;
        }
    }
}

// ---------------------------------------------------------------------------
// Split fp32 -> bf16 hi/lo, 16B-chunk-swizzled: chunk c of row m stored at
// chunk (c ^ (m&7)) within its 64-elem K-tile. Inner dim K=256.
// ---------------------------------------------------------------------------
__global__ __launch_bounds__(256)
void split_kernel(const float* __restrict__ x,  short* __restrict__ xh,  short* __restrict__ xl,
                  const float* __restrict__ wq, short* __restrict__ wqh, short* __restrict__ wql,
                  const float* __restrict__ wp, short* __restrict__ wph, short* __restrict__ wpl)
{
    int bid = blockIdx.x;
    const float* src; short* dh; short* dl; int base8;
    if (bid < 1024)      { src = x;  dh = xh;  dl = xl;  base8 = bid * 256; }
    else if (bid < 1120) { src = wq; dh = wqh; dl = wql; base8 = (bid-1024) * 256; }
    else                 { src = wp; dh = wph; dl = wpl; base8 = (bid-1120) * 256; }
    int e0 = (base8 + (int)threadIdx.x) * 8;
    int m  = e0 >> 8;
    int k  = e0 & 255;
    int kt = k >> 6, c = (k >> 3) & 7;
    float4 f0 = *(const float4*)(src + e0);
    float4 f1 = *(const float4*)(src + e0 + 4);
    float v[8] = {f0.x,f0.y,f0.z,f0.w,f1.x,f1.y,f1.z,f1.w};
    v8s hi, lo;
    #pragma unroll
    for (int j = 0; j < 8; ++j) {
        uint32_t u1 = fbits(v[j]) + 0x8000u;
        hi[j] = (short)(u1 >> 16);
        lo[j] = bf_rh(v[j] - ffrom(u1 & 0xFFFF0000u));
    }
    int dst = m*256 + kt*64 + ((c ^ (m & 7)) << 3);
    *(v8s*)&dh[dst] = hi;
    *(v8s*)&dl[dst] = lo;
}

// ---------------------------------------------------------------------------
// Split-bf16 MFMA GEMM: C = A(MxK=256) * W(NxK=256)^T + bias.
// PASSES=3: hi*hi + lo*hi + hi*lo (fp32-grade). PASSES=1: hi*hi only.
// MODE 1 (qkv): v band (n0>=512) runs 1-pass; q/k bands 3-pass. Epilogue:
//   q: l2norm + qe + softplus(temp)*10 (log2e folded), plain hi/lo;
//   k: l2norm, hi/lo stored KEY-PERMUTED within 64-tiles and chunk-swizzled;
//   v: bf16 transposed to vt[bh][32][1024] (chunk-swizzled) via LDS.
// MODE 0: plain fp32 C [M][N].
// ---------------------------------------------------------------------------
template<int MODE, int PASSES>
__global__ __launch_bounds__(256)
void gemm_mfma(const short* __restrict__ Ahi, const short* __restrict__ Alo,
               const short* __restrict__ Whi, const short* __restrict__ Wlo,
               const float* __restrict__ bias, float* __restrict__ C,
               short* __restrict__ qhi, short* __restrict__ qlo,
               short* __restrict__ khi, short* __restrict__ klo,
               short* __restrict__ vt,
               const float* __restrict__ qe, const float* __restrict__ temp,
               int N)
{
    __shared__ __align__(16) char smem[49152];
    short* Ah = (short*)smem;          // [128][64]
    short* Al = Ah + 128*64;
    short* Wh = Al + 128*64;           // [64][64]
    short* Wl = Wh + 64*64;

    int tid  = threadIdx.x;
    int w    = tid >> 6;
    int lane = tid & 63;
    int t    = lane & 15;
    int quad = lane >> 4;
    int m0 = blockIdx.y * 128, n0 = blockIdx.x * 64;
    int Mw = (w >> 1) * 64, Nw = (w & 1) * 32;
    const bool onep = (PASSES == 1) || (MODE == 1 && n0 >= 512);

    v4f acc[4][2];
    #pragma unroll
    for (int mt = 0; mt < 4; ++mt)
        #pragma unroll
        for (int nt = 0; nt < 2; ++nt) acc[mt][nt] = (v4f){0,0,0,0};

    int lr8 = lane >> 3, lc8 = lane & 7;
    #pragma unroll 1
    for (int kt = 0; kt < 4; ++kt) {
        __syncthreads();
        #pragma unroll
        for (int i = 0; i < 4; ++i) {
            size_t grow = (size_t)(m0 + w*32 + i*8 + lr8) * 256 + kt*64 + lc8*8;
            int ls = (w*32 + i*8) * 64;
            gld16(Ahi + grow, Ah + ls);
            if (!onep) gld16(Alo + grow, Al + ls);
        }
        #pragma unroll
        for (int i = 0; i < 2; ++i) {
            size_t grow = (size_t)(n0 + w*16 + i*8 + lr8) * 256 + kt*64 + lc8*8;
            int ls = (w*16 + i*8) * 64;
            gld16(Whi + grow, Wh + ls);
            if (!onep) gld16(Wlo + grow, Wl + ls);
        }
        __syncthreads();
        #pragma unroll
        for (int kk = 0; kk < 2; ++kk) {
            int cp = ((kk*4 + quad) ^ (t & 7)) << 3;
            v8s bh8[2], bl8[2];
            #pragma unroll
            for (int nt = 0; nt < 2; ++nt) {
                int rowi = Nw + nt*16 + t;
                bh8[nt] = *(const v8s*)&Wh[rowi*64 + cp];
                if (!onep) bl8[nt] = *(const v8s*)&Wl[rowi*64 + cp];
            }
            #pragma unroll
            for (int mt = 0; mt < 4; ++mt) {
                int rowi = Mw + mt*16 + t;
                v8s ah = *(const v8s*)&Ah[rowi*64 + cp];
                v8s al;
                if (!onep) al = *(const v8s*)&Al[rowi*64 + cp];
                #pragma unroll
                for (int nt = 0; nt < 2; ++nt) {
                    acc[mt][nt] = MFMA(ah, bh8[nt], acc[mt][nt]);
                    if (!onep) {
                        acc[mt][nt] = MFMA(al, bh8[nt], acc[mt][nt]);
                        acc[mt][nt] = MFMA(ah, bl8[nt], acc[mt][nt]);
                    }
                }
            }
        }
    }

    // bias
    #pragma unroll
    for (int nt = 0; nt < 2; ++nt) {
        float bv = bias[n0 + Nw + nt*16 + t];
        #pragma unroll
        for (int mt = 0; mt < 4; ++mt)
            #pragma unroll
            for (int r = 0; r < 4; ++r) acc[mt][nt][r] += bv;
    }

    if (MODE == 0) {
        #pragma unroll
        for (int mt = 0; mt < 4; ++mt)
            #pragma unroll
            for (int r = 0; r < 4; ++r) {
                int m = m0 + Mw + mt*16 + quad*4 + r;
                #pragma unroll
                for (int nt = 0; nt < 2; ++nt) {
                    int n = n0 + Nw + nt*16 + t;
                    C[(size_t)m * N + n] = acc[mt][nt][r];
                }
            }
    } else {
        int which = n0 >> 8;
        if (which < 2) {
            int head = ((n0 + Nw) >> 5) & 7;
            float scale = 0.f;
            if (which == 0)
                scale = log1pf(__expf(temp[head])) * 10.0f;  // softplus*ln(1024)*log2e
            #pragma unroll
            for (int mt = 0; mt < 4; ++mt)
                #pragma unroll
                for (int r = 0; r < 4; ++r) {
                    float a0 = acc[mt][0][r], a1 = acc[mt][1][r];
                    float s = a0*a0 + a1*a1;
                    s += __shfl_xor(s, 1); s += __shfl_xor(s, 2);
                    s += __shfl_xor(s, 4); s += __shfl_xor(s, 8);
                    float inv = 1.0f / fmaxf(sqrtf(s), 1e-12f);
                    int m = m0 + Mw + mt*16 + quad*4 + r;
                    int b = m >> 10, nrow = m & 1023;
                    if (which == 0) {
                        size_t rowoff = (((size_t)b*8 + head)*1024 + nrow) * 32;
                        #pragma unroll
                        for (int nt = 0; nt < 2; ++nt) {
                            int d = nt*16 + t;
                            float val = (acc[mt][nt][r] * inv + qe[head*32 + d]) * scale;
                            uint32_t u1 = fbits(val) + 0x8000u;
                            qhi[rowoff + d] = (short)(u1 >> 16);
                            qlo[rowoff + d] = bf_rh(val - ffrom(u1 & 0xFFFF0000u));
                        }
                    } else {
                        // key-permuted position within 64-tile + chunk swizzle
                        int kk = nrow & 63;
                        int p  = (kk & 3)*16 + (kk >> 2);
                        int prow = (nrow & ~63) | p;
                        int swk = (kk >> 3) & 3;
                        size_t rowoff = (((size_t)b*8 + head)*1024 + prow) * 32;
                        #pragma unroll
                        for (int nt = 0; nt < 2; ++nt) {
                            int d = nt*16 + t;
                            int c = d >> 3;
                            int dpos = ((c ^ swk) << 3) | (d & 7);
                            float val = acc[mt][nt][r] * inv;
                            uint32_t u1 = fbits(val) + 0x8000u;
                            khi[rowoff + dpos] = (short)(u1 >> 16);
                            klo[rowoff + dpos] = bf_rh(val - ffrom(u1 & 0xFFFF0000u));
                        }
                    }
                }
        } else {
            // v: transpose via LDS, write vt[bh][dim][key] bf16, tile-swizzled
            __syncthreads();
            short* VT = (short*)smem;        // [64][136]
            #pragma unroll
            for (int mt = 0; mt < 4; ++mt)
                #pragma unroll
                for (int nt = 0; nt < 2; ++nt) {
                    int cl = Nw + nt*16 + t;
                    #pragma unroll
                    for (int r = 0; r < 4; ++r) {
                        int rl = Mw + mt*16 + quad*4 + r;
                        VT[cl*136 + rl] = bf_rh(acc[mt][nt][r]);
                    }
                }
            __syncthreads();
            int b = m0 >> 10;
            int keybase = m0 & 1023;
            int headbase = ((n0 - 512) >> 5) & 7;
            int cl = tid >> 2;
            int dim = cl & 31;
            int hd  = headbase + (cl >> 5);
            size_t obase = (((size_t)b*8 + hd)*32 + dim) * 1024 + keybase;
            #pragma unroll
            for (int p = 0; p < 4; ++p) {
                int ci  = (tid & 3) * 4 + p;
                int ktl = ci >> 3, c = ci & 7;
                v8s val = *(const v8s*)&VT[cl*136 + ktl*64 + c*8];
                *(v8s*)&vt[obase + ktl*64 + ((c ^ (dim & 7)) << 3)] = val;
            }
        }
    }
}

// ---------------------------------------------------------------------------
// MFMA flash attention in exp2 domain (log2e folded into q-scale and bias;
// no max subtraction — constant factor cancels in p/l). Double-buffered K/V
// LDS, bf16 bias as MFMA C-init, key-permuted K so P stores are packed b64
// writes via v_perm. Output: swizzled bf16 y (proj GEMM is 1-pass).
// ---------------------------------------------------------------------------
__global__ __launch_bounds__(256)
void attn_mfma(const short* __restrict__ qhi, const short* __restrict__ qlo,
               const short* __restrict__ khi, const short* __restrict__ klo,
               const short* __restrict__ vt,  const short* __restrict__ biasM,
               short* __restrict__ yhi)
{
    __shared__ __align__(16) short Khi_s[2][2048];   // [64][32]
    __shared__ __align__(16) short Klo_s[2][2048];
    __shared__ __align__(16) short Vt_s[2][2048];    // [32][64]
    __shared__ __align__(16) short Ps[4][16][68];    // per-wave P (cols=keys)

    int bh  = blockIdx.x >> 4;
    int qt  = blockIdx.x & 15;
    int h   = bh & 7;
    int b   = bh >> 3;
    int tid = threadIdx.x;
    int w    = tid >> 6;
    int lane = tid & 63;
    int t    = lane & 15;
    int quad = lane >> 4;

    size_t qoff = ((size_t)bh*1024 + qt*64 + w*16 + t) * 32 + quad*8;
    v8s qfh = *(const v8s*)(qhi + qoff);
    v8s qfl = *(const v8s*)(qlo + qoff);

    v4f Oacc[2] = {{0,0,0,0},{0,0,0,0}};
    float lsum[4] = {0,0,0,0};

    size_t kgbase = (size_t)bh * 32768;
    const short* bmb = biasM + ((size_t)(h*64 + qt*4 + w) * 16) * 1024 + lane*4;
    int qrow0 = qt*64 + w*16 + quad*4;
    int swzS = (quad ^ ((t >> 1) & 3)) << 3;
    int lr8 = lane >> 3, lc8 = lane & 7;

    // stage tile 0 into buffer 0
    gld16(khi + kgbase + w*512 + lane*8, &Khi_s[0][w*512]);
    gld16(klo + kgbase + w*512 + lane*8, &Klo_s[0][w*512]);
    gld16(vt + kgbase + (size_t)(w*8 + lr8)*1024 + lc8*8, &Vt_s[0][w*512]);
    // bias for tile 0 (packed bf16 pairs, software-pipelined in registers)
    uint2 curb[4];
    #pragma unroll
    for (int g = 0; g < 4; ++g) curb[g] = *(const uint2*)(bmb + g*256);

    #pragma unroll 1
    for (int kt = 0; kt < 16; ++kt) {
        int cur = kt & 1;
        __syncthreads();   // prior reads of nxt done; cur's staged writes landed
        uint2 nxtb[4];
        if (kt < 15) {
            int nkt = kt + 1, nb = cur ^ 1;
            gld16(khi + kgbase + (size_t)nkt*2048 + w*512 + lane*8, &Khi_s[nb][w*512]);
            gld16(klo + kgbase + (size_t)nkt*2048 + w*512 + lane*8, &Klo_s[nb][w*512]);
            gld16(vt + kgbase + (size_t)(w*8 + lr8)*1024 + nkt*64 + lc8*8, &Vt_s[nb][w*512]);
            const short* bp = bmb + (size_t)nkt*1024;
            #pragma unroll
            for (int g = 0; g < 4; ++g) nxtb[g] = *(const uint2*)(bp + g*256);
        }

        // S = bias + Q' K^T (split-bf16, 3 passes), exp2 domain
        v4f S[4];
        #pragma unroll
        for (int g = 0; g < 4; ++g) {
            v8s bh8 = *(const v8s*)&Khi_s[cur][(g*16 + t)*32 + swzS];
            v8s bl8 = *(const v8s*)&Klo_s[cur][(g*16 + t)*32 + swzS];
            v4f c;
            c[0] = ffrom(curb[g].x << 16);
            c[1] = ffrom(curb[g].x & 0xFFFF0000u);
            c[2] = ffrom(curb[g].y << 16);
            c[3] = ffrom(curb[g].y & 0xFFFF0000u);
            c = MFMA(qfh, bh8, c);
            c = MFMA(qfl, bh8, c);
            c = MFMA(qfh, bl8, c);
            S[g] = c;
        }

        // p = exp2(S); P cols are contiguous actual keys 4t+g -> packed b64
        #pragma unroll
        for (int r = 0; r < 4; ++r) {
            float p0 = EXP2(S[0][r]);
            float p1 = EXP2(S[1][r]);
            float p2 = EXP2(S[2][r]);
            float p3 = EXP2(S[3][r]);
            lsum[r] += (p0 + p1) + (p2 + p3);
            uint2 pk;
            pk.x = pack_bf_rh(p0, p1);
            pk.y = pack_bf_rh(p2, p3);
            *(uint2*)&Ps[w][quad*4 + r][t*4] = pk;
        }

        // O += P V (same-wave LDS dependency, no barrier)
        #pragma unroll
        for (int ks = 0; ks < 2; ++ks) {
            v8s pf = *(const v8s*)&Ps[w][t][ks*32 + quad*8];
            int vsw = ((ks*4 + quad) ^ (t & 7)) << 3;
            #pragma unroll
            for (int g = 0; g < 2; ++g) {
                v8s vf = *(const v8s*)&Vt_s[cur][(g*16 + t)*64 + vsw];
                Oacc[g] = MFMA(pf, vf, Oacc[g]);
            }
        }
        #pragma unroll
        for (int g = 0; g < 4; ++g) curb[g] = nxtb[g];
    }

    // epilogue: reduce l, normalize, write swizzled bf16 y
    #pragma unroll
    for (int r = 0; r < 4; ++r) {
        float l = lsum[r];
        l += __shfl_xor(l, 1); l += __shfl_xor(l, 2);
        l += __shfl_xor(l, 4); l += __shfl_xor(l, 8);
        float inv = 1.0f / l;
        int qrow = qrow0 + r;
        int m = b*1024 + qrow;
        size_t mbase = (size_t)m * 256;
        int mk = m & 7;
        #pragma unroll
        for (int g = 0; g < 2; ++g) {
            float o = Oacc[g][r] * inv;
            int c = h*4 + g*2 + (t >> 3);
            int chp = ((c ^ mk) << 3) | (t & 7);
            yhi[mbase + chp] = bf_rh(o);
        }
    }
}

// ---------------------------------------------------------------------------
extern "C" void kernel_launch(void* const* d_in, const int* in_sizes, int n_in,
                              void* d_out, int out_size, void* d_ws, size_t ws_size,
                              hipStream_t stream)
{
    const float* x     = (const float*)d_in[0];
    const int*   rpi   = (const int*)d_in[3];
    const float* rct   = (const float*)d_in[4];
    const float* qkvw  = (const float*)d_in[5];
    const float* qkvb  = (const float*)d_in[6];
    const float* qe    = (const float*)d_in[7];
    const float* temp  = (const float*)d_in[8];
    const float* projw = (const float*)d_in[9];
    const float* projb = (const float*)d_in[10];
    const float* fc1w  = (const float*)d_in[11];
    const float* fc1b  = (const float*)d_in[12];
    const float* fc2w  = (const float*)d_in[13];
    const float* fc2b  = (const float*)d_in[14];

    char* p = (char*)d_ws;
    float* tblf  = (float*)p;  p += 131072;
    short* xh    = (short*)p;  p += 4194304;   // reused as yhi after QKV GEMM
    short* xl    = (short*)p;  p += 4194304;
    short* wqh   = (short*)p;  p += 393216;
    short* wql   = (short*)p;  p += 393216;
    short* wph   = (short*)p;  p += 131072;
    short* wpl   = (short*)p;  p += 131072;
    short* qh    = (short*)p;  p += 4194304;
    short* ql    = (short*)p;  p += 4194304;
    short* kh    = (short*)p;  p += 4194304;
    short* kl    = (short*)p;  p += 4194304;
    short* vt    = (short*)p;  p += 4194304;
    short* biasM = (short*)p;  p += 16777216;
    float* out   = (float*)d_out;

    // 1) zero the cpb accumulator, then CPB MLP (parallel over j-chunks)
    hipMemsetAsync(tblf, 0, 8*3969*sizeof(float), stream);
    cpb_kernel<<<dim3(16,8), 256, 0, stream>>>(rct, fc1w, fc1b, fc2w, fc2b, tblf);

    // 2) fragment-ordered bf16 bias, log2e folded (batch-independent)
    bias_mat<<<512, 256, 0, stream>>>(tblf, rpi, biasM);

    // 3) split x / qkv_w / proj_w into swizzled bf16 hi/lo
    split_kernel<<<1152, 256, 0, stream>>>(x, xh, xl, qkvw, wqh, wql, projw, wph, wpl);

    // 4) QKV GEMM + fused l2norm/scale/split + V transpose (v band 1-pass)
    dim3 g1(768/64, 8192/128);
    gemm_mfma<1,3><<<g1, 256, 0, stream>>>(xh, xl, wqh, wql, qkvb, nullptr,
                                           qh, ql, kh, kl, vt, qe, temp, 768);

    // 5) MFMA attention (exp2 domain) -> swizzled bf16 y (aliases xh)
    attn_mfma<<<1024, 256, 0, stream>>>(qh, ql, kh, kl, vt, biasM, xh);

    // 6) output projection (1-pass bf16) -> d_out (fp32)
    dim3 g2(256/64, 8192/128);
    gemm_mfma<0,1><<<g2, 256, 0, stream>>>(xh, nullptr, wph, nullptr, projb, out,
                                           nullptr, nullptr, nullptr, nullptr,
                                           nullptr, nullptr, nullptr, 256);
}

// Round 7
// 159.766 us; speedup vs baseline: 1.2405x; 1.0590x over previous
//
#include <hip/hip_runtime.h>
#include <hip/hip_bf16.h>
#include <cstddef>
#include <cstdint>

typedef float v4f __attribute__((ext_vector_type(4)));
typedef short v8s __attribute__((ext_vector_type(8)));
typedef _Float16 v8h __attribute__((ext_vector_type(8)));

__device__ __forceinline__ uint32_t fbits(float x){ uint32_t u; __builtin_memcpy(&u,&x,4); return u; }
__device__ __forceinline__ float ffrom(uint32_t u){ float f; __builtin_memcpy(&f,&u,4); return f; }
// round-half-up bf16
__device__ __forceinline__ short bf_rh(float x){ return (short)((fbits(x)+0x8000u)>>16); }
__device__ __forceinline__ uint32_t pack_bf_rh(float a, float b){
    uint32_t ua = fbits(a)+0x8000u, ub = fbits(b)+0x8000u;
#if __has_builtin(__builtin_amdgcn_perm)
    return __builtin_amdgcn_perm(ub, ua, 0x07060302u);
#else
    return (ua>>16) | (ub & 0xFFFF0000u);
#endif
}
// fp16 (RNE) stored in a short
__device__ __forceinline__ short f2h(float x){ _Float16 h = (_Float16)x; short s; __builtin_memcpy(&s,&h,2); return s; }
__device__ __forceinline__ v8h as_h(v8s s){ v8h h; __builtin_memcpy(&h,&s,16); return h; }
#if __has_builtin(__builtin_amdgcn_exp2f)
#define EXP2(x) __builtin_amdgcn_exp2f(x)
#else
#define EXP2(x) exp2f(x)
#endif

__device__ __forceinline__ void gld16(const void* g, void* l) {
    __builtin_amdgcn_global_load_lds(
        (const __attribute__((address_space(1))) unsigned int*)g,
        (__attribute__((address_space(3))) unsigned int*)l, 16, 0, 0);
}
#define MFMA(a,b,c)  __builtin_amdgcn_mfma_f32_16x16x32_bf16((a),(b),(c),0,0,0)
#define MFMAH(a,b,c) __builtin_amdgcn_mfma_f32_16x16x32_f16((a),(b),(c),0,0,0)

#define LOG2E 1.4426950408889634f

// ---------------------------------------------------------------------------
// CPB MLP, single launch, no atomics: 63 blocks x 63 rows; 4 threads per row
// split the 512 hidden dim, shuffle-reduce partials.
// ---------------------------------------------------------------------------
__global__ __launch_bounds__(256)
void cpb_kernel(const float* __restrict__ rct,
                const float* __restrict__ fc1w, const float* __restrict__ fc1b,
                const float* __restrict__ fc2w, const float* __restrict__ fc2b,
                float* __restrict__ table)
{
    __shared__ float s1[1024];
    __shared__ float sb[512];
    __shared__ float s2[4096];
    int tid = threadIdx.x;
    for (int i = tid; i < 1024; i += 256) s1[i] = fc1w[i];
    for (int i = tid; i < 512;  i += 256) sb[i] = fc1b[i];
    for (int i = tid; i < 4096; i += 256) s2[i] = fc2w[i];
    __syncthreads();
    int rl = tid >> 2, jp = tid & 3;
    bool ok = rl < 63;
    int r = blockIdx.x * 63 + rl;
    float c0 = ok ? rct[2*r]   : 0.f;
    float c1 = ok ? rct[2*r+1] : 0.f;
    float a[8] = {0,0,0,0,0,0,0,0};
    int j0 = jp * 128;
    #pragma unroll 4
    for (int j = j0; j < j0 + 128; ++j) {
        float hv = fmaxf(c0*s1[2*j] + c1*s1[2*j+1] + sb[j], 0.0f);
        #pragma unroll
        for (int hh = 0; hh < 8; ++hh) a[hh] += hv * s2[hh*512 + j];
    }
    #pragma unroll
    for (int hh = 0; hh < 8; ++hh) {
        a[hh] += __shfl_xor(a[hh], 1);
        a[hh] += __shfl_xor(a[hh], 2);
    }
    if (ok && jp == 0) {
        #pragma unroll
        for (int hh = 0; hh < 8; ++hh) table[hh*3969 + r] = a[hh] + fc2b[hh];
    }
}

// ---------------------------------------------------------------------------
// Materialize relative-position bias as bf16, scaled by log2(e), in MFMA
// C-fragment order matching the permuted K staging (key kt*64 + 4t + g).
// Layout: [h][q16(64)][kt(16)][g(4)][lane(64)][4 shorts] = 16 MB.
// ---------------------------------------------------------------------------
__global__ __launch_bounds__(256)
void bias_mat(const float* __restrict__ tblf, const int* __restrict__ rpi,
              short* __restrict__ biasM)
{
    __shared__ float tb[3969];
    int h   = blockIdx.x >> 6;
    int q16 = blockIdx.x & 63;
    int tid = threadIdx.x;
    int w = tid >> 6, lane = tid & 63, t = lane & 15, quad = lane >> 4;
    for (int i = tid; i < 3969; i += 256) tb[i] = tblf[h*3969 + i] * LOG2E;
    __syncthreads();
    int row0 = q16*16 + quad*4;
    #pragma unroll 1
    for (int kk = 0; kk < 4; ++kk) {
        int kt = w*4 + kk;
        #pragma unroll
        for (int g = 0; g < 4; ++g) {
            float o[4];
            #pragma unroll
            for (int r = 0; r < 4; ++r)
                o[r] = tb[rpi[(size_t)(row0 + r)*1024 + kt*64 + 4*t + g]];
            uint2 pk;
            pk.x = pack_bf_rh(o[0], o[1]);
            pk.y = pack_bf_rh(o[2], o[3]);
            size_t base = ((((size_t)(h*64 + q16)*16 + kt)*4 + g)*64 + lane)*4;
            *(uint2*)(biasM + base) = pk;
        }
    }
}

// ---------------------------------------------------------------------------
// fp32 -> fp16, 16B-chunk-swizzled: chunk c of row m stored at chunk
// (c ^ (m&7)) within its 64-elem K-tile. Inner dim K=256.
// ---------------------------------------------------------------------------
__global__ __launch_bounds__(256)
void split_kernel(const float* __restrict__ x,  short* __restrict__ xh,
                  const float* __restrict__ wq, short* __restrict__ wqh,
                  const float* __restrict__ wp, short* __restrict__ wph)
{
    int bid = blockIdx.x;
    const float* src; short* dh; int base8;
    if (bid < 1024)      { src = x;  dh = xh;  base8 = bid * 256; }
    else if (bid < 1120) { src = wq; dh = wqh; base8 = (bid-1024) * 256; }
    else                 { src = wp; dh = wph; base8 = (bid-1120) * 256; }
    int e0 = (base8 + (int)threadIdx.x) * 8;
    int m  = e0 >> 8;
    int k  = e0 & 255;
    int kt = k >> 6, c = (k >> 3) & 7;
    float4 f0 = *(const float4*)(src + e0);
    float4 f1 = *(const float4*)(src + e0 + 4);
    float v[8] = {f0.x,f0.y,f0.z,f0.w,f1.x,f1.y,f1.z,f1.w};
    v8s hi;
    #pragma unroll
    for (int j = 0; j < 8; ++j) hi[j] = f2h(v[j]);
    int dst = m*256 + kt*64 + ((c ^ (m & 7)) << 3);
    *(v8s*)&dh[dst] = hi;
}

// ---------------------------------------------------------------------------
// fp16 1-pass MFMA GEMM: C = A(MxK=256) * W(NxK=256)^T + bias.
// TM=128, TN=64, BK=64, 256 threads = 4 waves (2x2 wave grid).
// MODE 0: plain fp32 C [M][N] (proj).
// MODE 1 (qkv): q: l2norm + qe + softplus(temp)*10, fp16 plain layout;
//   k: l2norm, fp16 KEY-PERMUTED within 64-tiles + chunk-swizzled;
//   v: bf16 transposed to vt[bh][32][1024] (chunk-swizzled) via LDS.
// ---------------------------------------------------------------------------
template<int MODE>
__global__ __launch_bounds__(256)
void gemm_mfma(const short* __restrict__ Ah_g, const short* __restrict__ Wh_g,
               const float* __restrict__ bias, float* __restrict__ C,
               short* __restrict__ qh, short* __restrict__ kh,
               short* __restrict__ vt,
               const float* __restrict__ qe, const float* __restrict__ temp,
               int N)
{
    __shared__ __align__(16) char smem[24576];
    short* Ah = (short*)smem;          // [128][64] fp16
    short* Wh = Ah + 128*64;           // [64][64]  fp16

    int tid  = threadIdx.x;
    int w    = tid >> 6;
    int lane = tid & 63;
    int t    = lane & 15;
    int quad = lane >> 4;
    int m0 = blockIdx.y * 128, n0 = blockIdx.x * 64;
    int Mw = (w >> 1) * 64, Nw = (w & 1) * 32;

    v4f acc[4][2];
    #pragma unroll
    for (int mt = 0; mt < 4; ++mt)
        #pragma unroll
        for (int nt = 0; nt < 2; ++nt) acc[mt][nt] = (v4f){0,0,0,0};

    int lr8 = lane >> 3, lc8 = lane & 7;
    #pragma unroll 1
    for (int kt = 0; kt < 4; ++kt) {
        __syncthreads();
        #pragma unroll
        for (int i = 0; i < 4; ++i) {
            size_t grow = (size_t)(m0 + w*32 + i*8 + lr8) * 256 + kt*64 + lc8*8;
            gld16(Ah_g + grow, Ah + (w*32 + i*8) * 64);
        }
        #pragma unroll
        for (int i = 0; i < 2; ++i) {
            size_t grow = (size_t)(n0 + w*16 + i*8 + lr8) * 256 + kt*64 + lc8*8;
            gld16(Wh_g + grow, Wh + (w*16 + i*8) * 64);
        }
        __syncthreads();
        #pragma unroll
        for (int kk = 0; kk < 2; ++kk) {
            int cp = ((kk*4 + quad) ^ (t & 7)) << 3;
            v8h bh8[2];
            #pragma unroll
            for (int nt = 0; nt < 2; ++nt)
                bh8[nt] = *(const v8h*)&Wh[(Nw + nt*16 + t)*64 + cp];
            #pragma unroll
            for (int mt = 0; mt < 4; ++mt) {
                v8h ah = *(const v8h*)&Ah[(Mw + mt*16 + t)*64 + cp];
                #pragma unroll
                for (int nt = 0; nt < 2; ++nt)
                    acc[mt][nt] = MFMAH(ah, bh8[nt], acc[mt][nt]);
            }
        }
    }

    // bias
    #pragma unroll
    for (int nt = 0; nt < 2; ++nt) {
        float bv = bias[n0 + Nw + nt*16 + t];
        #pragma unroll
        for (int mt = 0; mt < 4; ++mt)
            #pragma unroll
            for (int r = 0; r < 4; ++r) acc[mt][nt][r] += bv;
    }

    if (MODE == 0) {
        #pragma unroll
        for (int mt = 0; mt < 4; ++mt)
            #pragma unroll
            for (int r = 0; r < 4; ++r) {
                int m = m0 + Mw + mt*16 + quad*4 + r;
                #pragma unroll
                for (int nt = 0; nt < 2; ++nt)
                    C[(size_t)m * N + n0 + Nw + nt*16 + t] = acc[mt][nt][r];
            }
    } else {
        int which = n0 >> 8;
        if (which < 2) {
            int head = ((n0 + Nw) >> 5) & 7;
            float scale = 0.f;
            if (which == 0)
                scale = log1pf(__expf(temp[head])) * 10.0f;  // softplus*ln(1024)*log2e
            #pragma unroll
            for (int mt = 0; mt < 4; ++mt)
                #pragma unroll
                for (int r = 0; r < 4; ++r) {
                    float a0 = acc[mt][0][r], a1 = acc[mt][1][r];
                    float s = a0*a0 + a1*a1;
                    s += __shfl_xor(s, 1); s += __shfl_xor(s, 2);
                    s += __shfl_xor(s, 4); s += __shfl_xor(s, 8);
                    float inv = 1.0f / fmaxf(sqrtf(s), 1e-12f);
                    int m = m0 + Mw + mt*16 + quad*4 + r;
                    int b = m >> 10, nrow = m & 1023;
                    if (which == 0) {
                        size_t rowoff = (((size_t)b*8 + head)*1024 + nrow) * 32;
                        #pragma unroll
                        for (int nt = 0; nt < 2; ++nt) {
                            int d = nt*16 + t;
                            float val = (acc[mt][nt][r] * inv + qe[head*32 + d]) * scale;
                            qh[rowoff + d] = f2h(val);
                        }
                    } else {
                        int kk = nrow & 63;
                        int p  = (kk & 3)*16 + (kk >> 2);
                        int prow = (nrow & ~63) | p;
                        int swk = (kk >> 3) & 3;
                        size_t rowoff = (((size_t)b*8 + head)*1024 + prow) * 32;
                        #pragma unroll
                        for (int nt = 0; nt < 2; ++nt) {
                            int d = nt*16 + t;
                            int dpos = (((d >> 3) ^ swk) << 3) | (d & 7);
                            kh[rowoff + dpos] = f2h(acc[mt][nt][r] * inv);
                        }
                    }
                }
        } else {
            // v: transpose via LDS, write vt[bh][dim][key] bf16, tile-swizzled
            __syncthreads();
            short* VT = (short*)smem;        // [64][136]
            #pragma unroll
            for (int mt = 0; mt < 4; ++mt)
                #pragma unroll
                for (int nt = 0; nt < 2; ++nt) {
                    int cl = Nw + nt*16 + t;
                    #pragma unroll
                    for (int r = 0; r < 4; ++r) {
                        int rl = Mw + mt*16 + quad*4 + r;
                        VT[cl*136 + rl] = bf_rh(acc[mt][nt][r]);
                    }
                }
            __syncthreads();
            int b = m0 >> 10;
            int keybase = m0 & 1023;
            int headbase = ((n0 - 512) >> 5) & 7;
            int cl = tid >> 2;
            int dim = cl & 31;
            int hd  = headbase + (cl >> 5);
            size_t obase = (((size_t)b*8 + hd)*32 + dim) * 1024 + keybase;
            #pragma unroll
            for (int p = 0; p < 4; ++p) {
                int ci  = (tid & 3) * 4 + p;
                int ktl = ci >> 3, c = ci & 7;
                v8s val = *(const v8s*)&VT[cl*136 + ktl*64 + c*8];
                *(v8s*)&vt[obase + ktl*64 + ((c ^ (dim & 7)) << 3)] = val;
            }
        }
    }
}

// ---------------------------------------------------------------------------
// MFMA flash attention, exp2 domain, fp16 QK^T (1 MFMA per 16x16 S tile),
// bf16 PV (P can reach 2^46 — needs bf16 range). Double-buffered K/V LDS,
// bf16 bias as MFMA C-init, key-permuted K so P stores are packed b64 writes.
// Output: swizzled fp16 y for the 1-pass fp16 proj GEMM.
// ---------------------------------------------------------------------------
__global__ __launch_bounds__(256)
void attn_mfma(const short* __restrict__ qh, const short* __restrict__ kh,
               const short* __restrict__ vt,  const short* __restrict__ biasM,
               short* __restrict__ yh)
{
    __shared__ __align__(16) short Kh_s[2][2048];   // [64][32] fp16
    __shared__ __align__(16) short Vt_s[2][2048];   // [32][64] bf16
    __shared__ __align__(16) short Ps[4][16][68];   // per-wave P (bf16, cols=keys)

    int bh  = blockIdx.x >> 4;
    int qt  = blockIdx.x & 15;
    int h   = bh & 7;
    int b   = bh >> 3;
    int tid = threadIdx.x;
    int w    = tid >> 6;
    int lane = tid & 63;
    int t    = lane & 15;
    int quad = lane >> 4;

    size_t qoff = ((size_t)bh*1024 + qt*64 + w*16 + t) * 32 + quad*8;
    v8h qf = *(const v8h*)(qh + qoff);

    v4f Oacc[2] = {{0,0,0,0},{0,0,0,0}};
    float lsum[4] = {0,0,0,0};

    size_t kgbase = (size_t)bh * 32768;
    const short* bmb = biasM + ((size_t)(h*64 + qt*4 + w) * 16) * 1024 + lane*4;
    int qrow0 = qt*64 + w*16 + quad*4;
    int swzS = (quad ^ ((t >> 1) & 3)) << 3;
    int lr8 = lane >> 3, lc8 = lane & 7;

    // stage tile 0 into buffer 0
    gld16(kh + kgbase + w*512 + lane*8, &Kh_s[0][w*512]);
    gld16(vt + kgbase + (size_t)(w*8 + lr8)*1024 + lc8*8, &Vt_s[0][w*512]);
    uint2 curb[4];
    #pragma unroll
    for (int g = 0; g < 4; ++g) curb[g] = *(const uint2*)(bmb + g*256);

    #pragma unroll 1
    for (int kt = 0; kt < 16; ++kt) {
        int cur = kt & 1;
        __syncthreads();
        uint2 nxtb[4];
        if (kt < 15) {
            int nkt = kt + 1, nb = cur ^ 1;
            gld16(kh + kgbase + (size_t)nkt*2048 + w*512 + lane*8, &Kh_s[nb][w*512]);
            gld16(vt + kgbase + (size_t)(w*8 + lr8)*1024 + nkt*64 + lc8*8, &Vt_s[nb][w*512]);
            const short* bp = bmb + (size_t)nkt*1024;
            #pragma unroll
            for (int g = 0; g < 4; ++g) nxtb[g] = *(const uint2*)(bp + g*256);
        }

        // S = bias + Q K^T (fp16, 1 pass), exp2 domain
        v4f S[4];
        #pragma unroll
        for (int g = 0; g < 4; ++g) {
            v8h kb = *(const v8h*)&Kh_s[cur][(g*16 + t)*32 + swzS];
            v4f c;
            c[0] = ffrom(curb[g].x << 16);
            c[1] = ffrom(curb[g].x & 0xFFFF0000u);
            c[2] = ffrom(curb[g].y << 16);
            c[3] = ffrom(curb[g].y & 0xFFFF0000u);
            S[g] = MFMAH(qf, kb, c);
        }

        // p = exp2(S); P cols are contiguous actual keys 4t+g -> packed b64
        #pragma unroll
        for (int r = 0; r < 4; ++r) {
            float p0 = EXP2(S[0][r]);
            float p1 = EXP2(S[1][r]);
            float p2 = EXP2(S[2][r]);
            float p3 = EXP2(S[3][r]);
            lsum[r] += (p0 + p1) + (p2 + p3);
            uint2 pk;
            pk.x = pack_bf_rh(p0, p1);
            pk.y = pack_bf_rh(p2, p3);
            *(uint2*)&Ps[w][quad*4 + r][t*4] = pk;
        }

        // O += P V (same-wave LDS dependency, no barrier)
        #pragma unroll
        for (int ks = 0; ks < 2; ++ks) {
            v8s pf = *(const v8s*)&Ps[w][t][ks*32 + quad*8];
            int vsw = ((ks*4 + quad) ^ (t & 7)) << 3;
            #pragma unroll
            for (int g = 0; g < 2; ++g) {
                v8s vf = *(const v8s*)&Vt_s[cur][(g*16 + t)*64 + vsw];
                Oacc[g] = MFMA(pf, vf, Oacc[g]);
            }
        }
        #pragma unroll
        for (int g = 0; g < 4; ++g) curb[g] = nxtb[g];
    }

    // epilogue: reduce l, normalize, write swizzled fp16 y
    #pragma unroll
    for (int r = 0; r < 4; ++r) {
        float l = lsum[r];
        l += __shfl_xor(l, 1); l += __shfl_xor(l, 2);
        l += __shfl_xor(l, 4); l += __shfl_xor(l, 8);
        float inv = 1.0f / l;
        int qrow = qrow0 + r;
        int m = b*1024 + qrow;
        size_t mbase = (size_t)m * 256;
        int mk = m & 7;
        #pragma unroll
        for (int g = 0; g < 2; ++g) {
            float o = Oacc[g][r] * inv;
            int c = h*4 + g*2 + (t >> 3);
            int chp = ((c ^ mk) << 3) | (t & 7);
            yh[mbase + chp] = f2h(o);
        }
    }
}

// ---------------------------------------------------------------------------
extern "C" void kernel_launch(void* const* d_in, const int* in_sizes, int n_in,
                              void* d_out, int out_size, void* d_ws, size_t ws_size,
                              hipStream_t stream)
{
    const float* x     = (const float*)d_in[0];
    const int*   rpi   = (const int*)d_in[3];
    const float* rct   = (const float*)d_in[4];
    const float* qkvw  = (const float*)d_in[5];
    const float* qkvb  = (const float*)d_in[6];
    const float* qe    = (const float*)d_in[7];
    const float* temp  = (const float*)d_in[8];
    const float* projw = (const float*)d_in[9];
    const float* projb = (const float*)d_in[10];
    const float* fc1w  = (const float*)d_in[11];
    const float* fc1b  = (const float*)d_in[12];
    const float* fc2w  = (const float*)d_in[13];
    const float* fc2b  = (const float*)d_in[14];

    char* p = (char*)d_ws;
    float* tblf  = (float*)p;  p += 131072;
    short* xh    = (short*)p;  p += 4194304;   // reused as y (fp16) after attn
    short* wqh   = (short*)p;  p += 393216;
    short* wph   = (short*)p;  p += 131072;
    short* qh    = (short*)p;  p += 4194304;
    short* kh    = (short*)p;  p += 4194304;
    short* vt    = (short*)p;  p += 4194304;
    short* biasM = (short*)p;  p += 16777216;
    float* out   = (float*)d_out;

    // 1) CPB MLP -> fp32 table [8][3969] (single launch, no atomics)
    cpb_kernel<<<63, 256, 0, stream>>>(rct, fc1w, fc1b, fc2w, fc2b, tblf);

    // 2) fragment-ordered bf16 bias, log2e folded (batch-independent)
    bias_mat<<<512, 256, 0, stream>>>(tblf, rpi, biasM);

    // 3) x / qkv_w / proj_w -> swizzled fp16
    split_kernel<<<1152, 256, 0, stream>>>(x, xh, qkvw, wqh, projw, wph);

    // 4) QKV GEMM (fp16 1-pass) + fused l2norm/scale + V transpose
    dim3 g1(768/64, 8192/128);
    gemm_mfma<1><<<g1, 256, 0, stream>>>(xh, wqh, qkvb, nullptr,
                                         qh, kh, vt, qe, temp, 768);

    // 5) MFMA attention (fp16 QK^T, exp2 domain) -> swizzled fp16 y
    attn_mfma<<<1024, 256, 0, stream>>>(qh, kh, vt, biasM, xh);

    // 6) output projection (fp16 1-pass) -> d_out (fp32)
    dim3 g2(256/64, 8192/128);
    gemm_mfma<0><<<g2, 256, 0, stream>>>(xh, wph, projb, out,
                                         nullptr, nullptr, nullptr,
                                         nullptr, nullptr, 256);
}